// Round 1
// baseline (543.795 us; speedup 1.0000x reference)
//
#include <hip/hip_runtime.h>
#include <hip/hip_cooperative_groups.h>

namespace cg = cooperative_groups;

typedef unsigned short u16;
typedef unsigned int u32;
typedef __bf16 bf16x8 __attribute__((ext_vector_type(8)));
typedef float f32x4 __attribute__((ext_vector_type(4)));
typedef u16 u16x8 __attribute__((ext_vector_type(8)));

__device__ __forceinline__ u16 f2bf(float f) {
    __bf16 h = (__bf16)f;
    return __builtin_bit_cast(u16, h);
}
__device__ __forceinline__ float bf2f(u16 u) {
    unsigned int x = ((unsigned int)u) << 16;
    return __builtin_bit_cast(float, x);
}

union FragU { u16x8 u; bf16x8 v; };

// ---------------- workspace layout (float offsets) ----------------
constexpr size_t WB2F  = 0;
constexpr size_t WB3F  = 18432;
constexpr size_t WBV2  = 36864;
constexpr size_t W1T   = 55296;
constexpr size_t W2T   = 57344;
constexpr size_t X1    = 59392;
constexpr size_t X2    = 317440;
constexpr size_t FEATBF= 575488;
constexpr size_t NVOFF = 833536;
constexpr size_t CFOFF = 862208;
constexpr size_t NOVEL = 890880;
constexpr size_t Y1    = 905216;
constexpr size_t Y2    = 1363968;

// ================= conv phase helper (64ch in, 3x3, MFMA) ==================
template<int W, int NPX, int LTILES, int LOCH, int NT>
__device__ __forceinline__ void conv_mfma_phase(
    int bid, int t, const u16* __restrict__ in, const u16* __restrict__ wbf,
    const float* __restrict__ bias, u16* __restrict__ outp)
{
    constexpr int H = 32;
    const int pxt  = bid % LTILES;
    const int ochi = (bid / LTILES) % LOCH;
    const int m    = bid / (LTILES * LOCH);
    const int ochb = ochi * (NT * 16);
    const int w = t >> 6, lane = t & 63, q = lane >> 4, l15 = lane & 15;
    const int base = pxt * 64;
    const u16* im = in + (size_t)m * NPX * 64;
    const int pxA = base + w * 16 + l15;
    const int yA = pxA / W, xA = pxA - yA * W;
    const bool pxok = (pxA < NPX);

    f32x4 acc[NT];
#pragma unroll
    for (int nt = 0; nt < NT; ++nt) acc[nt] = f32x4{0.f, 0.f, 0.f, 0.f};

#pragma unroll
    for (int tap = 0; tap < 9; ++tap) {
        const int dy = tap / 3 - 1, dx = tap % 3 - 1;
        const bool valid = pxok && (yA + dy >= 0) && (yA + dy < H)
                                && (xA + dx >= 0) && (xA + dx < W);
        const u16* ap = im + (size_t)(pxA + dy * W + dx) * 64;
        FragU a0, a1;
        if (valid) {
            a0 = *(const FragU*)(ap + q * 8);
            a1 = *(const FragU*)(ap + 32 + q * 8);
        } else {
#pragma unroll
            for (int jj = 0; jj < 8; ++jj) { a0.u[jj] = 0; a1.u[jj] = 0; }
        }
#pragma unroll
        for (int nt = 0; nt < NT; ++nt) {
            const u16* bp = wbf + tap * 4096 + (ochb + nt * 16 + l15) * 64;
            FragU b0 = *(const FragU*)(bp + q * 8);
            FragU b1 = *(const FragU*)(bp + 32 + q * 8);
            acc[nt] = __builtin_amdgcn_mfma_f32_16x16x32_bf16(a0.v, b0.v, acc[nt], 0, 0, 0);
            acc[nt] = __builtin_amdgcn_mfma_f32_16x16x32_bf16(a1.v, b1.v, acc[nt], 0, 0, 0);
        }
    }

#pragma unroll
    for (int nt = 0; nt < NT; ++nt) {
        const float bb = bias[ochb + nt * 16 + l15];
#pragma unroll
        for (int e = 0; e < 4; ++e) {
            int pxs = base + w * 16 + q * 4 + e;
            if (pxs < NPX)
                outp[((size_t)m * NPX + pxs) * 64 + ochb + nt * 16 + l15] =
                    f2bf(fmaxf(acc[nt][e] + bb, 0.f));
        }
    }
}

// ================= fused cooperative kernel ================================
__global__ __launch_bounds__(256, 2) void fused_kernel(
    const float* __restrict__ lf,   const float* __restrict__ flow,
    const float* __restrict__ wp,   const float* __restrict__ pl,
    const float* __restrict__ pr,
    const float* __restrict__ frw1, const float* __restrict__ frb1,
    const float* __restrict__ frw2, const float* __restrict__ frb2,
    const float* __restrict__ frw3, const float* __restrict__ frb3,
    const float* __restrict__ mw1,  const float* __restrict__ mb1,
    const float* __restrict__ mw2,  const float* __restrict__ mb2,
    const float* __restrict__ mw3,  const float* __restrict__ mb3,
    const float* __restrict__ cw,   const float* __restrict__ cb,
    const float* __restrict__ vrw1, const float* __restrict__ vrb1,
    const float* __restrict__ vrw2, const float* __restrict__ vrb2,
    const float* __restrict__ vrw3, const float* __restrict__ vrb3,
    float* ws, float* __restrict__ out)
{
    // shared scratch, aliased per phase. max = mlp: 1792+1024+1024+36864 = 40704 B
    __shared__ __align__(16) unsigned char smem[40704];

    const int t = threadIdx.x;
    const int bid = blockIdx.x;
    cg::grid_group grid = cg::this_grid();

    // ---------------- P0: conv1 (3->64) + weight prep ----------------------
    if (bid < 256) {
        constexpr int W = 63, NPX = 2016, H = 32;
        const int og = bid & 7;
        const int m  = bid >> 6;
        const int px = ((bid >> 3) & 7) * 256 + t;
        if (px < NPX) {
            const int y = px / W, x = px - y * W;
            float acc[8];
#pragma unroll
            for (int oc = 0; oc < 8; ++oc) acc[oc] = frb1[og * 8 + oc];
#pragma unroll
            for (int cin = 0; cin < 3; ++cin) {
                const float* ip = (cin == 0 ? flow : (cin == 1 ? lf : wp)) + (size_t)m * NPX;
                float tap[9];
#pragma unroll
                for (int dy = 0; dy < 3; ++dy) {
                    int yy = y + dy - 1;
                    bool ry = (yy >= 0) && (yy < H);
#pragma unroll
                    for (int dx = 0; dx < 3; ++dx) {
                        int xx = x + dx - 1;
                        tap[dy * 3 + dx] = (ry && xx >= 0 && xx < W) ? ip[yy * W + xx] : 0.f;
                    }
                }
#pragma unroll
                for (int oc = 0; oc < 8; ++oc) {
                    const float* wr = frw1 + (size_t)(og * 8 + oc) * 27 + cin * 9;
#pragma unroll
                    for (int j = 0; j < 9; ++j) acc[oc] = fmaf(tap[j], wr[j], acc[oc]);
                }
            }
            u16x8 pk;
#pragma unroll
            for (int oc = 0; oc < 8; ++oc) pk[oc] = f2bf(fmaxf(acc[oc], 0.f));
            *(u16x8*)((u16*)(ws + X1) + ((size_t)m * NPX + px) * 64 + og * 8) = pk;
        }
    } else if (bid < 320) {
        const int tid = (bid - 256) * 256 + t;       // 0..16383
        u16* wb2 = (u16*)(ws + WB2F);
        u16* wb3 = (u16*)(ws + WB3F);
        u16* wbv = (u16*)(ws + WBV2);
        u16* w1tp = (u16*)(ws + W1T);
        u16* w2tp = (u16*)(ws + W2T);
        for (int i = tid; i < 36864; i += 16384) {
            int tap = i >> 12, och = (i >> 6) & 63, cin = i & 63;
            size_t sgl = (size_t)och * 576 + cin * 9 + tap;
            wb2[i] = f2bf(frw2[sgl]);
            wb3[i] = f2bf(frw3[sgl]);
            wbv[i] = f2bf(vrw2[sgl]);
        }
        for (int i = tid; i < 4096; i += 16384) {
            int col = i >> 6, r = i & 63;
            w1tp[i] = f2bf(mw1[(1 + r) * 64 + col]);
            w2tp[i] = f2bf(mw2[r * 64 + col]);
        }
    }
    grid.sync();

    // ---------------- P1: feature conv2 (64->64), 512 blocks ---------------
    conv_mfma_phase<63, 2016, 32, 4, 1>(bid, t,
        (const u16*)(ws + X1), (const u16*)(ws + WB2F), frb2, (u16*)(ws + X2));
    grid.sync();

    // ---------------- P2: feature conv3 (64->64), 512 blocks ---------------
    conv_mfma_phase<63, 2016, 32, 4, 1>(bid, t,
        (const u16*)(ws + X2), (const u16*)(ws + WB3F), frb3, (u16*)(ws + FEATBF));
    grid.sync();

    // ---------------- P3: MLP (all 512 blocks) -----------------------------
    {
        constexpr int SBS = 72;
        float* s_vec  = (float*)smem;             // 448 floats
        float* s_flow = (float*)(smem + 1792);    // 256
        float* s_epi  = (float*)(smem + 2816);    // 256
        u16*   s_base = (u16*)(smem + 3840);      // 256*72 u16

        const u16* feat = (const u16*)(ws + FEATBF);
        const u16* w1t  = (const u16*)(ws + W1T);
        const u16* w2t  = (const u16*)(ws + W2T);
        float* nv_out = ws + NVOFF;
        float* cf_out = ws + CFOFF;

        const int blk = bid;
        const int bs = blk >> 7;
        const int n0 = (blk & 127) * 8;
        const int b = bs >> 1, s = bs & 1;
        const int w = t >> 6, lane = t & 63, q = lane >> 4, l15 = lane & 15;
        (void)b;

        if (t < 64) {
            s_vec[t]       = mb1[t];
            s_vec[64 + t]  = mb2[t];
            s_vec[128 + t] = mw3[t];
            s_vec[192 + t] = cw[t];
            s_vec[256 + t] = mw1[t];             // row 0: flow weight
            s_vec[320 + t] = mw1[65 * 64 + t];   // row 65: spatial
            s_vec[384 + t] = mw1[66 * 64 + t];   // row 66: ang
        }
        {
            int nl = t >> 5, k = t & 31;
            int n = n0 + nl;
            int a = (bs * 32 + (n >> 5)) * 63 + (n & 31) + k;
            s_flow[t] = flow[a];
            s_epi[t]  = lf[a];
        }
        __syncthreads();

        const float b3s = mb3[0];
        const float cbs = cb[0];

        FragU w1b[2][4];
#pragma unroll
        for (int ks = 0; ks < 2; ++ks)
#pragma unroll
            for (int nt = 0; nt < 4; ++nt)
                w1b[ks][nt] = *(const FragU*)(w1t + (nt * 16 + l15) * 64 + ks * 32 + q * 8);

        float w1r0pl[4], w1r65pl[4], b1pl[4];
#pragma unroll
        for (int nt = 0; nt < 4; ++nt) {
            int j1 = nt * 16 + l15;
            w1r0pl[nt]  = s_vec[256 + j1];
            w1r65pl[nt] = s_vec[320 + j1];
            b1pl[nt]    = s_vec[j1];
        }

#pragma unroll
        for (int mt = 0; mt < 4; ++mt) {
            const int rbase = w * 64 + mt * 16;
            FragU af[2];
            {
                int r = rbase + l15;
                int n = n0 + (r >> 5);
                int pos = (n >> 5) * 63 + (n & 31) + (r & 31);
                const u16* fp = feat + ((size_t)bs * 2016 + pos) * 64;
                af[0] = *(const FragU*)(fp + q * 8);
                af[1] = *(const FragU*)(fp + 32 + q * 8);
            }
            f32x4 flow4 = *(const f32x4*)(s_flow + rbase + q * 4);
#pragma unroll
            for (int nt = 0; nt < 4; ++nt) {
                f32x4 d = {0.f, 0.f, 0.f, 0.f};
                d = __builtin_amdgcn_mfma_f32_16x16x32_bf16(af[0].v, w1b[0][nt].v, d, 0, 0, 0);
                d = __builtin_amdgcn_mfma_f32_16x16x32_bf16(af[1].v, w1b[1][nt].v, d, 0, 0, 0);
#pragma unroll
                for (int e = 0; e < 4; ++e) {
                    int r = rbase + q * 4 + e;
                    int k = r & 31;
                    float val = d[e] + flow4[e] * w1r0pl[nt]
                              + (float)(k - 16) * w1r65pl[nt] + b1pl[nt];
                    s_base[r * SBS + nt * 16 + l15] = f2bf(val);
                }
            }
        }
        __syncthreads();

        FragU w2a[4][2];
#pragma unroll
        for (int mt = 0; mt < 4; ++mt)
#pragma unroll
            for (int ks = 0; ks < 2; ++ks)
                w2a[mt][ks] = *(const FragU*)(w2t + (mt * 16 + l15) * 64 + ks * 32 + q * 8);

        float w66pl[2][8];
#pragma unroll
        for (int ks = 0; ks < 2; ++ks)
#pragma unroll
            for (int jj = 0; jj < 8; ++jj)
                w66pl[ks][jj] = s_vec[384 + ks * 32 + q * 8 + jj];

        float b2pl[4][4], w3pl[4][4], cwpl[4][4];
#pragma unroll
        for (int mt = 0; mt < 4; ++mt)
#pragma unroll
            for (int e = 0; e < 4; ++e) {
                b2pl[mt][e] = s_vec[64 + mt * 16 + q * 4 + e];
                w3pl[mt][e] = s_vec[128 + mt * 16 + q * 4 + e];
                cwpl[mt][e] = s_vec[192 + mt * 16 + q * 4 + e];
            }
        float epi_pl[4];
#pragma unroll
        for (int nt = 0; nt < 4; ++nt) epi_pl[nt] = s_epi[w * 64 + nt * 16 + l15];

        for (int v = 0; v < 7; ++v) {
            float ang = (s == 0) ? -(float)(v + 1) : (float)(7 - v);
            f32x4 acc[4][4];
#pragma unroll
            for (int nt = 0; nt < 4; ++nt) {
                FragU bfr[2];
#pragma unroll
                for (int ks = 0; ks < 2; ++ks) {
                    const u16x8 raw = *(const u16x8*)(s_base + (w * 64 + nt * 16 + l15) * SBS + ks * 32 + q * 8);
#pragma unroll
                    for (int jj = 0; jj < 8; ++jj) {
                        float xv = bf2f(raw[jj]);
                        float hv = fmaxf(xv + ang * w66pl[ks][jj], 0.f);
                        bfr[ks].u[jj] = f2bf(hv);
                    }
                }
#pragma unroll
                for (int mt = 0; mt < 4; ++mt) {
                    f32x4 d = {0.f, 0.f, 0.f, 0.f};
                    d = __builtin_amdgcn_mfma_f32_16x16x32_bf16(w2a[mt][0].v, bfr[0].v, d, 0, 0, 0);
                    d = __builtin_amdgcn_mfma_f32_16x16x32_bf16(w2a[mt][1].v, bfr[1].v, d, 0, 0, 0);
                    acc[mt][nt] = d;
                }
            }
            float wl[4], cfl[4];
#pragma unroll
            for (int nt = 0; nt < 4; ++nt) {
                float wls = 0.f, cfs = 0.f;
#pragma unroll
                for (int mt = 0; mt < 4; ++mt)
#pragma unroll
                    for (int e = 0; e < 4; ++e) {
                        float h2 = fmaxf(acc[mt][nt][e] + b2pl[mt][e], 0.f);
                        wls += h2 * w3pl[mt][e];
                        cfs += h2 * cwpl[mt][e];
                    }
                wls += __shfl_xor(wls, 16); wls += __shfl_xor(wls, 32);
                cfs += __shfl_xor(cfs, 16); cfs += __shfl_xor(cfs, 32);
                wl[nt]  = wls + b3s;
                cfl[nt] = cfs;
            }
#pragma unroll
            for (int ni = 0; ni < 2; ++ni) {
                float a0 = wl[ni * 2], a1 = wl[ni * 2 + 1];
                float mx = fmaxf(a0, a1);
#pragma unroll
                for (int msk = 1; msk <= 8; msk <<= 1) mx = fmaxf(mx, __shfl_xor(mx, msk));
                float e0 = __expf(a0 - mx), e1 = __expf(a1 - mx);
                float ssum = e0 + e1;
                float nvp = e0 * epi_pl[ni * 2] + e1 * epi_pl[ni * 2 + 1];
                float cfp = cfl[ni * 2] + cfl[ni * 2 + 1];
#pragma unroll
                for (int msk = 1; msk <= 8; msk <<= 1) {
                    ssum += __shfl_xor(ssum, msk);
                    nvp  += __shfl_xor(nvp, msk);
                    cfp  += __shfl_xor(cfp, msk);
                }
                if (lane == 0) {
                    int n = n0 + w * 2 + ni;
                    size_t idx = ((size_t)((bs >> 1) * 7 + v) * 2 + s) * 1024 + n;
                    nv_out[idx] = nvp / ssum;
                    cf_out[idx] = cfp * (1.f / 32.f) + cbs;
                }
            }
        }
    }
    grid.sync();

    // ---------------- P4: refine conv1 + conf combine (448 blocks) ---------
    if (bid < 448) {
        float (*pn)[32] = (float (*)[32])smem;
        const float* nv = ws + NVOFF;
        const float* cf = ws + CFOFF;
        u16* outy1 = (u16*)(ws + Y1);
        float* novel = ws + NOVEL;

        const int og = bid & 7, pt = (bid >> 3) & 3, m = bid >> 5;
        const int y0 = pt * 8;

        for (int i = t; i < 320; i += 256) {
            int ri = i >> 5, col = i & 31;
            int gy = y0 - 1 + ri;
            float vv = 0.f;
            if (gy >= 0 && gy < 32) {
                int n = gy * 32 + col;
                size_t i0 = ((size_t)m * 2) * 1024 + n;
                size_t i1 = i0 + 1024;
                float c0 = cf[i0], c1 = cf[i1];
                float mx = fmaxf(c0, c1);
                float e0 = __expf(c0 - mx), e1 = __expf(c1 - mx);
                vv = (e0 * nv[i0] + e1 * nv[i1]) / (e0 + e1);
            }
            pn[ri][col] = vv;
        }
        __syncthreads();

        const int px = y0 * 32 + t;
        const int y = px >> 5, x = px & 31;
        if (og == 0) novel[(size_t)m * 1024 + px] = pn[y - y0 + 1][x];

        float acc[8];
#pragma unroll
        for (int oc = 0; oc < 8; ++oc) acc[oc] = vrb1[og * 8 + oc];

        {
            float tap[9];
#pragma unroll
            for (int dy = 0; dy < 3; ++dy) {
#pragma unroll
                for (int dx = 0; dx < 3; ++dx) {
                    int gx = x + dx - 1;
                    tap[dy * 3 + dx] = (gx >= 0 && gx < 32) ? pn[y - y0 + dy][gx] : 0.f;
                }
            }
#pragma unroll
            for (int oc = 0; oc < 8; ++oc) {
                const float* wr = vrw1 + (size_t)(og * 8 + oc) * 27;
#pragma unroll
                for (int j = 0; j < 9; ++j) acc[oc] = fmaf(tap[j], wr[j], acc[oc]);
            }
        }
#pragma unroll
        for (int cin = 1; cin < 3; ++cin) {
            const float* ip = (cin == 1 ? pl : pr) + (size_t)m * 1024;
            float tap[9];
#pragma unroll
            for (int dy = 0; dy < 3; ++dy) {
                int yy = y + dy - 1;
                bool ry = (yy >= 0) && (yy < 32);
#pragma unroll
                for (int dx = 0; dx < 3; ++dx) {
                    int xx = x + dx - 1;
                    tap[dy * 3 + dx] = (ry && xx >= 0 && xx < 32) ? ip[yy * 32 + xx] : 0.f;
                }
            }
#pragma unroll
            for (int oc = 0; oc < 8; ++oc) {
                const float* wr = vrw1 + (size_t)(og * 8 + oc) * 27 + cin * 9;
#pragma unroll
                for (int j = 0; j < 9; ++j) acc[oc] = fmaf(tap[j], wr[j], acc[oc]);
            }
        }
        u16x8 pk;
#pragma unroll
        for (int oc = 0; oc < 8; ++oc) pk[oc] = f2bf(fmaxf(acc[oc], 0.f));
        *(u16x8*)(outy1 + ((size_t)m * 1024 + px) * 64 + og * 8) = pk;
    }
    grid.sync();

    // ---------------- P5: refine conv2 (64->64), 448 blocks ----------------
    if (bid < 448)
        conv_mfma_phase<32, 1024, 16, 2, 2>(bid, t,
            (const u16*)(ws + Y1), (const u16*)(ws + WBV2), vrb2, (u16*)(ws + Y2));
    grid.sync();

    // ---------------- P6: conv3 (64->1) + residual (56 blocks) -------------
    if (bid < 56) {
        float* sw3 = (float*)smem;
        const u16* in3 = (const u16*)(ws + Y2);
        const float* resid = ws + NOVEL;
        for (int i = t; i < 576; i += 256) sw3[i] = vrw3[i];
        __syncthreads();

        const int tid = bid * 256 + t;
        const int m = tid >> 10, p = tid & 1023;
        const int y = p >> 5, x = p & 31;
        float a = vrb3[0] + resid[tid];
        const u16* im = in3 + ((size_t)m * 1024 + p) * 64;
#pragma unroll
        for (int dy = 0; dy < 3; ++dy) {
            int yy = y + dy - 1;
            if (yy < 0 || yy >= 32) continue;
#pragma unroll
            for (int dx = 0; dx < 3; ++dx) {
                int xx = x + dx - 1;
                if (xx < 0 || xx >= 32) continue;
                const u16* ip = im + (size_t)((dy - 1) * 32 + (dx - 1)) * 64;
                const int tap = dy * 3 + dx;
#pragma unroll
                for (int cg2 = 0; cg2 < 8; ++cg2) {
                    u16x8 raw = *(const u16x8*)(ip + cg2 * 8);
#pragma unroll
                    for (int e = 0; e < 8; ++e)
                        a = fmaf(bf2f(raw[e]), sw3[(cg2 * 8 + e) * 9 + tap], a);
                }
            }
        }
        out[tid] = a;
    }
}

// ================= original kernels kept as fallback =======================
__global__ __launch_bounds__(256) void conv1feat_kernel(
    const float* __restrict__ in0, const float* __restrict__ in1,
    const float* __restrict__ in2,
    const float* __restrict__ wts, const float* __restrict__ bias,
    u16* __restrict__ out,
    const float* __restrict__ frw2, const float* __restrict__ frw3,
    const float* __restrict__ vrw2,
    const float* __restrict__ mw1, const float* __restrict__ mw2,
    u16* __restrict__ wb2, u16* __restrict__ wb3, u16* __restrict__ wbv,
    u16* __restrict__ w1t, u16* __restrict__ w2t)
{
    constexpr int W = 63, NPX = 2016, H = 32;
    const int t = threadIdx.x;
    if (blockIdx.z == 4) {
        const int tid = (blockIdx.y * 8 + blockIdx.x) * 256 + t;
        for (int i = tid; i < 36864; i += 16384) {
            int tap = i >> 12, och = (i >> 6) & 63, cin = i & 63;
            size_t s = (size_t)och * 576 + cin * 9 + tap;
            wb2[i] = f2bf(frw2[s]);
            wb3[i] = f2bf(frw3[s]);
            wbv[i] = f2bf(vrw2[s]);
        }
        for (int i = tid; i < 4096; i += 16384) {
            int col = i >> 6, r = i & 63;
            w1t[i] = f2bf(mw1[(1 + r) * 64 + col]);
            w2t[i] = f2bf(mw2[r * 64 + col]);
        }
        return;
    }
    const int px = blockIdx.y * 256 + t;
    const int m = blockIdx.z;
    const int og = blockIdx.x;
    if (px >= NPX) return;
    const int y = px / W, x = px - y * W;

    float acc[8];
#pragma unroll
    for (int oc = 0; oc < 8; ++oc) acc[oc] = bias[og * 8 + oc];

#pragma unroll
    for (int cin = 0; cin < 3; ++cin) {
        const float* ip = (cin == 0 ? in0 : (cin == 1 ? in1 : in2)) + (size_t)m * NPX;
        float tap[9];
#pragma unroll
        for (int dy = 0; dy < 3; ++dy) {
            int yy = y + dy - 1;
            bool ry = (yy >= 0) && (yy < H);
#pragma unroll
            for (int dx = 0; dx < 3; ++dx) {
                int xx = x + dx - 1;
                tap[dy * 3 + dx] = (ry && xx >= 0 && xx < W) ? ip[yy * W + xx] : 0.f;
            }
        }
#pragma unroll
        for (int oc = 0; oc < 8; ++oc) {
            const float* wr = wts + (size_t)(og * 8 + oc) * 27 + cin * 9;
#pragma unroll
            for (int j = 0; j < 9; ++j) acc[oc] = fmaf(tap[j], wr[j], acc[oc]);
        }
    }
    u16x8 pk;
#pragma unroll
    for (int oc = 0; oc < 8; ++oc) pk[oc] = f2bf(fmaxf(acc[oc], 0.f));
    *(u16x8*)(out + ((size_t)m * NPX + px) * 64 + og * 8) = pk;
}

template<int W, int NPX>
__global__ __launch_bounds__(256) void convmfma_kernel(
    const u16* __restrict__ in, const u16* __restrict__ wbf,
    const float* __restrict__ bias, u16* __restrict__ out)
{
    constexpr int H = 32;
    const int t = threadIdx.x;
    const int base = blockIdx.x * 64;
    const int ochb = blockIdx.y * 32;
    const int m = blockIdx.z;
    const int w = t >> 6, lane = t & 63, q = lane >> 4, l15 = lane & 15;

    const u16* im = in + (size_t)m * NPX * 64;
    const int pxA = base + w * 16 + l15;
    const int yA = pxA / W, xA = pxA - yA * W;
    const bool pxok = (pxA < NPX);

    f32x4 acc[2];
#pragma unroll
    for (int nt = 0; nt < 2; ++nt) acc[nt] = f32x4{0.f, 0.f, 0.f, 0.f};

#pragma unroll
    for (int tap = 0; tap < 9; ++tap) {
        const int dy = tap / 3 - 1, dx = tap % 3 - 1;
        const bool valid = pxok && (yA + dy >= 0) && (yA + dy < H)
                                && (xA + dx >= 0) && (xA + dx < W);
        const u16* ap = im + (size_t)(pxA + dy * W + dx) * 64;
        FragU a0, a1;
        if (valid) {
            a0 = *(const FragU*)(ap + q * 8);
            a1 = *(const FragU*)(ap + 32 + q * 8);
        } else {
#pragma unroll
            for (int jj = 0; jj < 8; ++jj) { a0.u[jj] = 0; a1.u[jj] = 0; }
        }
#pragma unroll
        for (int nt = 0; nt < 2; ++nt) {
            const u16* bp = wbf + tap * 4096 + (ochb + nt * 16 + l15) * 64;
            FragU b0 = *(const FragU*)(bp + q * 8);
            FragU b1 = *(const FragU*)(bp + 32 + q * 8);
            acc[nt] = __builtin_amdgcn_mfma_f32_16x16x32_bf16(a0.v, b0.v, acc[nt], 0, 0, 0);
            acc[nt] = __builtin_amdgcn_mfma_f32_16x16x32_bf16(a1.v, b1.v, acc[nt], 0, 0, 0);
        }
    }

#pragma unroll
    for (int nt = 0; nt < 2; ++nt) {
        const float bb = bias[ochb + nt * 16 + l15];
#pragma unroll
        for (int e = 0; e < 4; ++e) {
            int pxs = base + w * 16 + q * 4 + e;
            if (pxs < NPX)
                out[((size_t)m * NPX + pxs) * 64 + ochb + nt * 16 + l15] =
                    f2bf(fmaxf(acc[nt][e] + bb, 0.f));
        }
    }
}

__global__ __launch_bounds__(256, 2) void mlp_mfma_kernel(
    const float* __restrict__ lf, const float* __restrict__ flow,
    const u16* __restrict__ feat,
    const u16* __restrict__ w1t, const u16* __restrict__ w2t,
    const float* __restrict__ w1, const float* __restrict__ b1,
    const float* __restrict__ b2,
    const float* __restrict__ w3, const float* __restrict__ b3g,
    const float* __restrict__ cw, const float* __restrict__ cbg,
    float* __restrict__ nv_out, float* __restrict__ cf_out)
{
    constexpr int SBS = 72;
    __shared__ __align__(16) float s_vec[7 * 64];
    __shared__ __align__(16) float s_flow[256];
    __shared__ __align__(16) float s_epi[256];
    __shared__ __align__(16) u16 s_base[256 * SBS];

    const int t = threadIdx.x;
    const int blk = blockIdx.x;
    const int bs = blk >> 7;
    const int n0 = (blk & 127) * 8;
    const int b = bs >> 1, s = bs & 1;
    const int w = t >> 6, lane = t & 63, q = lane >> 4, l15 = lane & 15;

    if (t < 64) {
        s_vec[t]       = b1[t];
        s_vec[64 + t]  = b2[t];
        s_vec[128 + t] = w3[t];
        s_vec[192 + t] = cw[t];
        s_vec[256 + t] = w1[t];
        s_vec[320 + t] = w1[65 * 64 + t];
        s_vec[384 + t] = w1[66 * 64 + t];
    }
    {
        int nl = t >> 5, k = t & 31;
        int n = n0 + nl;
        int a = (bs * 32 + (n >> 5)) * 63 + (n & 31) + k;
        s_flow[t] = flow[a];
        s_epi[t]  = lf[a];
    }
    __syncthreads();

    const float b3s = b3g[0];
    const float cbs = cbg[0];

    FragU w1b[2][4];
#pragma unroll
    for (int ks = 0; ks < 2; ++ks)
#pragma unroll
        for (int nt = 0; nt < 4; ++nt)
            w1b[ks][nt] = *(const FragU*)(w1t + (nt * 16 + l15) * 64 + ks * 32 + q * 8);

    float w1r0pl[4], w1r65pl[4], b1pl[4];
#pragma unroll
    for (int nt = 0; nt < 4; ++nt) {
        int j1 = nt * 16 + l15;
        w1r0pl[nt]  = s_vec[256 + j1];
        w1r65pl[nt] = s_vec[320 + j1];
        b1pl[nt]    = s_vec[j1];
    }

#pragma unroll
    for (int mt = 0; mt < 4; ++mt) {
        const int rbase = w * 64 + mt * 16;
        FragU af[2];
        {
            int r = rbase + l15;
            int n = n0 + (r >> 5);
            int pos = (n >> 5) * 63 + (n & 31) + (r & 31);
            const u16* fp = feat + ((size_t)bs * 2016 + pos) * 64;
            af[0] = *(const FragU*)(fp + q * 8);
            af[1] = *(const FragU*)(fp + 32 + q * 8);
        }
        f32x4 flow4 = *(const f32x4*)(s_flow + rbase + q * 4);
#pragma unroll
        for (int nt = 0; nt < 4; ++nt) {
            f32x4 d = {0.f, 0.f, 0.f, 0.f};
            d = __builtin_amdgcn_mfma_f32_16x16x32_bf16(af[0].v, w1b[0][nt].v, d, 0, 0, 0);
            d = __builtin_amdgcn_mfma_f32_16x16x32_bf16(af[1].v, w1b[1][nt].v, d, 0, 0, 0);
#pragma unroll
            for (int e = 0; e < 4; ++e) {
                int r = rbase + q * 4 + e;
                int k = r & 31;
                float val = d[e] + flow4[e] * w1r0pl[nt]
                          + (float)(k - 16) * w1r65pl[nt] + b1pl[nt];
                s_base[r * SBS + nt * 16 + l15] = f2bf(val);
            }
        }
    }
    __syncthreads();

    FragU w2a[4][2];
#pragma unroll
    for (int mt = 0; mt < 4; ++mt)
#pragma unroll
        for (int ks = 0; ks < 2; ++ks)
            w2a[mt][ks] = *(const FragU*)(w2t + (mt * 16 + l15) * 64 + ks * 32 + q * 8);

    float w66pl[2][8];
#pragma unroll
    for (int ks = 0; ks < 2; ++ks)
#pragma unroll
        for (int jj = 0; jj < 8; ++jj)
            w66pl[ks][jj] = s_vec[384 + ks * 32 + q * 8 + jj];

    float b2pl[4][4], w3pl[4][4], cwpl[4][4];
#pragma unroll
    for (int mt = 0; mt < 4; ++mt)
#pragma unroll
        for (int e = 0; e < 4; ++e) {
            b2pl[mt][e] = s_vec[64 + mt * 16 + q * 4 + e];
            w3pl[mt][e] = s_vec[128 + mt * 16 + q * 4 + e];
            cwpl[mt][e] = s_vec[192 + mt * 16 + q * 4 + e];
        }
    float epi_pl[4];
#pragma unroll
    for (int nt = 0; nt < 4; ++nt) epi_pl[nt] = s_epi[w * 64 + nt * 16 + l15];

    for (int v = 0; v < 7; ++v) {
        float ang = (s == 0) ? -(float)(v + 1) : (float)(7 - v);
        f32x4 acc[4][4];
#pragma unroll
        for (int nt = 0; nt < 4; ++nt) {
            FragU bfr[2];
#pragma unroll
            for (int ks = 0; ks < 2; ++ks) {
                const u16x8 raw = *(const u16x8*)(s_base + (w * 64 + nt * 16 + l15) * SBS + ks * 32 + q * 8);
#pragma unroll
                for (int jj = 0; jj < 8; ++jj) {
                    float xv = bf2f(raw[jj]);
                    float hv = fmaxf(xv + ang * w66pl[ks][jj], 0.f);
                    bfr[ks].u[jj] = f2bf(hv);
                }
            }
#pragma unroll
            for (int mt = 0; mt < 4; ++mt) {
                f32x4 d = {0.f, 0.f, 0.f, 0.f};
                d = __builtin_amdgcn_mfma_f32_16x16x32_bf16(w2a[mt][0].v, bfr[0].v, d, 0, 0, 0);
                d = __builtin_amdgcn_mfma_f32_16x16x32_bf16(w2a[mt][1].v, bfr[1].v, d, 0, 0, 0);
                acc[mt][nt] = d;
            }
        }
        float wl[4], cfl[4];
#pragma unroll
        for (int nt = 0; nt < 4; ++nt) {
            float wls = 0.f, cfs = 0.f;
#pragma unroll
            for (int mt = 0; mt < 4; ++mt)
#pragma unroll
                for (int e = 0; e < 4; ++e) {
                    float h2 = fmaxf(acc[mt][nt][e] + b2pl[mt][e], 0.f);
                    wls += h2 * w3pl[mt][e];
                    cfs += h2 * cwpl[mt][e];
                }
            wls += __shfl_xor(wls, 16); wls += __shfl_xor(wls, 32);
            cfs += __shfl_xor(cfs, 16); cfs += __shfl_xor(cfs, 32);
            wl[nt]  = wls + b3s;
            cfl[nt] = cfs;
        }
#pragma unroll
        for (int ni = 0; ni < 2; ++ni) {
            float a0 = wl[ni * 2], a1 = wl[ni * 2 + 1];
            float mx = fmaxf(a0, a1);
#pragma unroll
            for (int msk = 1; msk <= 8; msk <<= 1) mx = fmaxf(mx, __shfl_xor(mx, msk));
            float e0 = __expf(a0 - mx), e1 = __expf(a1 - mx);
            float ssum = e0 + e1;
            float nvp = e0 * epi_pl[ni * 2] + e1 * epi_pl[ni * 2 + 1];
            float cfp = cfl[ni * 2] + cfl[ni * 2 + 1];
#pragma unroll
            for (int msk = 1; msk <= 8; msk <<= 1) {
                ssum += __shfl_xor(ssum, msk);
                nvp  += __shfl_xor(nvp, msk);
                cfp  += __shfl_xor(cfp, msk);
            }
            if (lane == 0) {
                int n = n0 + w * 2 + ni;
                size_t idx = ((size_t)(b * 7 + v) * 2 + s) * 1024 + n;
                nv_out[idx] = nvp / ssum;
                cf_out[idx] = cfp * (1.f / 32.f) + cbs;
            }
        }
    }
}

__global__ __launch_bounds__(256) void refconv1_kernel(
    const float* __restrict__ nv, const float* __restrict__ cf,
    const float* __restrict__ pl, const float* __restrict__ pr,
    const float* __restrict__ wts, const float* __restrict__ bias,
    u16* __restrict__ out, float* __restrict__ novel)
{
    __shared__ float pn[10][32];
    const int t = threadIdx.x;
    const int og = blockIdx.x, pt = blockIdx.y, m = blockIdx.z;
    const int y0 = pt * 8;

    for (int i = t; i < 320; i += 256) {
        int ri = i >> 5, col = i & 31;
        int gy = y0 - 1 + ri;
        float vv = 0.f;
        if (gy >= 0 && gy < 32) {
            int n = gy * 32 + col;
            size_t i0 = ((size_t)m * 2) * 1024 + n;
            size_t i1 = i0 + 1024;
            float c0 = cf[i0], c1 = cf[i1];
            float mx = fmaxf(c0, c1);
            float e0 = __expf(c0 - mx), e1 = __expf(c1 - mx);
            vv = (e0 * nv[i0] + e1 * nv[i1]) / (e0 + e1);
        }
        pn[ri][col] = vv;
    }
    __syncthreads();

    const int px = y0 * 32 + t;
    const int y = px >> 5, x = px & 31;
    if (og == 0) novel[(size_t)m * 1024 + px] = pn[y - y0 + 1][x];

    float acc[8];
#pragma unroll
    for (int oc = 0; oc < 8; ++oc) acc[oc] = bias[og * 8 + oc];

    {
        float tap[9];
#pragma unroll
        for (int dy = 0; dy < 3; ++dy) {
#pragma unroll
            for (int dx = 0; dx < 3; ++dx) {
                int gx = x + dx - 1;
                tap[dy * 3 + dx] = (gx >= 0 && gx < 32) ? pn[y - y0 + dy][gx] : 0.f;
            }
        }
#pragma unroll
        for (int oc = 0; oc < 8; ++oc) {
            const float* wr = wts + (size_t)(og * 8 + oc) * 27;
#pragma unroll
            for (int j = 0; j < 9; ++j) acc[oc] = fmaf(tap[j], wr[j], acc[oc]);
        }
    }
#pragma unroll
    for (int cin = 1; cin < 3; ++cin) {
        const float* ip = (cin == 1 ? pl : pr) + (size_t)m * 1024;
        float tap[9];
#pragma unroll
        for (int dy = 0; dy < 3; ++dy) {
            int yy = y + dy - 1;
            bool ry = (yy >= 0) && (yy < 32);
#pragma unroll
            for (int dx = 0; dx < 3; ++dx) {
                int xx = x + dx - 1;
                tap[dy * 3 + dx] = (ry && xx >= 0 && xx < 32) ? ip[yy * 32 + xx] : 0.f;
            }
        }
#pragma unroll
        for (int oc = 0; oc < 8; ++oc) {
            const float* wr = wts + (size_t)(og * 8 + oc) * 27 + cin * 9;
#pragma unroll
            for (int j = 0; j < 9; ++j) acc[oc] = fmaf(tap[j], wr[j], acc[oc]);
        }
    }
    u16x8 pk;
#pragma unroll
    for (int oc = 0; oc < 8; ++oc) pk[oc] = f2bf(fmaxf(acc[oc], 0.f));
    *(u16x8*)(out + ((size_t)m * 1024 + px) * 64 + og * 8) = pk;
}

__global__ __launch_bounds__(256) void convlast_kernel(
    const u16* __restrict__ in, const float* __restrict__ wts,
    const float* __restrict__ bias, const float* __restrict__ resid,
    float* __restrict__ out)
{
    __shared__ float sw3[576];
    const int t = threadIdx.x;
    for (int i = t; i < 576; i += 256) sw3[i] = wts[i];
    __syncthreads();

    const int tid = blockIdx.x * 256 + t;
    const int m = tid >> 10, p = tid & 1023;
    const int y = p >> 5, x = p & 31;
    float a = bias[0] + resid[tid];
    const u16* im = in + ((size_t)m * 1024 + p) * 64;
#pragma unroll
    for (int dy = 0; dy < 3; ++dy) {
        int yy = y + dy - 1;
        if (yy < 0 || yy >= 32) continue;
#pragma unroll
        for (int dx = 0; dx < 3; ++dx) {
            int xx = x + dx - 1;
            if (xx < 0 || xx >= 32) continue;
            const u16* ip = im + (size_t)((dy - 1) * 32 + (dx - 1)) * 64;
            const int tap = dy * 3 + dx;
#pragma unroll
            for (int cg2 = 0; cg2 < 8; ++cg2) {
                u16x8 raw = *(const u16x8*)(ip + cg2 * 8);
#pragma unroll
                for (int e = 0; e < 8; ++e)
                    a = fmaf(bf2f(raw[e]), sw3[(cg2 * 8 + e) * 9 + tap], a);
            }
        }
    }
    out[tid] = a;
}

// ---------------- launch ----------------
extern "C" void kernel_launch(void* const* d_in, const int* in_sizes, int n_in,
                              void* d_out, int out_size, void* d_ws, size_t ws_size,
                              hipStream_t stream) {
    const float* lf   = (const float*)d_in[0];
    const float* flow = (const float*)d_in[1];
    const float* wp   = (const float*)d_in[2];
    const float* pl   = (const float*)d_in[3];
    const float* pr   = (const float*)d_in[4];
    const float* frw1 = (const float*)d_in[5];
    const float* frb1 = (const float*)d_in[6];
    const float* frw2 = (const float*)d_in[7];
    const float* frb2 = (const float*)d_in[8];
    const float* frw3 = (const float*)d_in[9];
    const float* frb3 = (const float*)d_in[10];
    const float* mw1  = (const float*)d_in[11];
    const float* mb1  = (const float*)d_in[12];
    const float* mw2  = (const float*)d_in[13];
    const float* mb2  = (const float*)d_in[14];
    const float* mw3  = (const float*)d_in[15];
    const float* mb3  = (const float*)d_in[16];
    const float* cw   = (const float*)d_in[17];
    const float* cb   = (const float*)d_in[18];
    const float* vrw1 = (const float*)d_in[19];
    const float* vrb1 = (const float*)d_in[20];
    const float* vrw2 = (const float*)d_in[21];
    const float* vrb2 = (const float*)d_in[22];
    const float* vrw3 = (const float*)d_in[23];
    const float* vrb3 = (const float*)d_in[24];
    float* ws = (float*)d_ws;
    float* outp = (float*)d_out;

    void* params[] = {
        &lf, &flow, &wp, &pl, &pr,
        &frw1, &frb1, &frw2, &frb2, &frw3, &frb3,
        &mw1, &mb1, &mw2, &mb2, &mw3, &mb3,
        &cw, &cb,
        &vrw1, &vrb1, &vrw2, &vrb2, &vrw3, &vrb3,
        &ws, &outp
    };

    hipError_t err = hipLaunchCooperativeKernel(
        (const void*)fused_kernel, dim3(512), dim3(256), params, 0u, stream);

    if (err != hipSuccess) {
        // fallback: original 7-kernel path
        conv1feat_kernel<<<dim3(8, 8, 5), 256, 0, stream>>>(
            flow, lf, wp, frw1, frb1,
            (u16*)(ws + X1),
            frw2, frw3, vrw2, mw1, mw2,
            (u16*)(ws + WB2F), (u16*)(ws + WB3F), (u16*)(ws + WBV2),
            (u16*)(ws + W1T), (u16*)(ws + W2T));

        convmfma_kernel<63, 2016><<<dim3(32, 2, 4), 256, 0, stream>>>(
            (const u16*)(ws + X1), (const u16*)(ws + WB2F), frb2,
            (u16*)(ws + X2));
        convmfma_kernel<63, 2016><<<dim3(32, 2, 4), 256, 0, stream>>>(
            (const u16*)(ws + X2), (const u16*)(ws + WB3F), frb3,
            (u16*)(ws + FEATBF));

        mlp_mfma_kernel<<<512, 256, 0, stream>>>(
            lf, flow, (const u16*)(ws + FEATBF),
            (const u16*)(ws + W1T), (const u16*)(ws + W2T),
            mw1, mb1, mb2, mw3, mb3, cw, cb,
            ws + NVOFF, ws + CFOFF);

        refconv1_kernel<<<dim3(8, 4, 14), 256, 0, stream>>>(
            ws + NVOFF, ws + CFOFF, pl, pr, vrw1, vrb1,
            (u16*)(ws + Y1), ws + NOVEL);
        convmfma_kernel<32, 1024><<<dim3(16, 2, 14), 256, 0, stream>>>(
            (const u16*)(ws + Y1), (const u16*)(ws + WBV2), vrb2,
            (u16*)(ws + Y2));
        convlast_kernel<<<56, 256, 0, stream>>>(
            (const u16*)(ws + Y2), vrw3, vrb3,
            ws + NOVEL, (float*)d_out);
    }
}

// Round 2
// 189.294 us; speedup vs baseline: 2.8728x; 2.8728x over previous
//
#include <hip/hip_runtime.h>

typedef unsigned short u16;
typedef unsigned int u32;
typedef __bf16 bf16x8 __attribute__((ext_vector_type(8)));
typedef float f32x4 __attribute__((ext_vector_type(4)));
typedef u16 u16x8 __attribute__((ext_vector_type(8)));

__device__ __forceinline__ u16 f2bf(float f) {
    __bf16 h = (__bf16)f;
    return __builtin_bit_cast(u16, h);
}
__device__ __forceinline__ float bf2f(u16 u) {
    unsigned int x = ((unsigned int)u) << 16;
    return __builtin_bit_cast(float, x);
}

union FragU { u16x8 u; bf16x8 v; };

// ---------------- workspace layout (float offsets) ----------------
constexpr size_t WB2F  = 0;        // frw2 bf16 [tap][och][cin]
constexpr size_t WB3F  = 18432;    // frw3
constexpr size_t WBV2  = 36864;    // vrw2
constexpr size_t W1T   = 55296;    // mw1 rows 1..64, [col][row-1]
constexpr size_t W2T   = 57344;    // mw2 transposed [j2][j1]
constexpr size_t X1    = 59392;    // 4*2016*64 u16 (ch-last bf16)
constexpr size_t X2    = 317440;
constexpr size_t FEATBF= 575488;
constexpr size_t NVOFF = 833536;   // [(b*7+v)*2+s][1024]
constexpr size_t CFOFF = 862208;

// ================= D1: feature conv1 (3->64) + weight prep ================
__global__ __launch_bounds__(256) void conv1feat_kernel(
    const float* __restrict__ in0, const float* __restrict__ in1,
    const float* __restrict__ in2,
    const float* __restrict__ wts, const float* __restrict__ bias,
    u16* __restrict__ out,
    const float* __restrict__ frw2, const float* __restrict__ frw3,
    const float* __restrict__ vrw2,
    const float* __restrict__ mw1, const float* __restrict__ mw2,
    u16* __restrict__ wb2, u16* __restrict__ wb3, u16* __restrict__ wbv,
    u16* __restrict__ w1t, u16* __restrict__ w2t)
{
    constexpr int W = 63, NPX = 2016, H = 32;
    const int t = threadIdx.x;
    if (blockIdx.z == 4) {
        const int tid = (blockIdx.y * 8 + blockIdx.x) * 256 + t;
        for (int i = tid; i < 36864; i += 16384) {
            int tap = i >> 12, och = (i >> 6) & 63, cin = i & 63;
            size_t s = (size_t)och * 576 + cin * 9 + tap;
            wb2[i] = f2bf(frw2[s]);
            wb3[i] = f2bf(frw3[s]);
            wbv[i] = f2bf(vrw2[s]);
        }
        for (int i = tid; i < 4096; i += 16384) {
            int col = i >> 6, r = i & 63;
            w1t[i] = f2bf(mw1[(1 + r) * 64 + col]);
            w2t[i] = f2bf(mw2[r * 64 + col]);
        }
        return;
    }
    const int px = blockIdx.y * 256 + t;
    const int m = blockIdx.z;
    const int og = blockIdx.x;
    if (px >= NPX) return;
    const int y = px / W, x = px - y * W;

    float acc[8];
#pragma unroll
    for (int oc = 0; oc < 8; ++oc) acc[oc] = bias[og * 8 + oc];

#pragma unroll
    for (int cin = 0; cin < 3; ++cin) {
        const float* ip = (cin == 0 ? in0 : (cin == 1 ? in1 : in2)) + (size_t)m * NPX;
        float tap[9];
#pragma unroll
        for (int dy = 0; dy < 3; ++dy) {
            int yy = y + dy - 1;
            bool ry = (yy >= 0) && (yy < H);
#pragma unroll
            for (int dx = 0; dx < 3; ++dx) {
                int xx = x + dx - 1;
                tap[dy * 3 + dx] = (ry && xx >= 0 && xx < W) ? ip[yy * W + xx] : 0.f;
            }
        }
#pragma unroll
        for (int oc = 0; oc < 8; ++oc) {
            const float* wr = wts + (size_t)(og * 8 + oc) * 27 + cin * 9;
#pragma unroll
            for (int j = 0; j < 9; ++j) acc[oc] = fmaf(tap[j], wr[j], acc[oc]);
        }
    }
    u16x8 pk;
#pragma unroll
    for (int oc = 0; oc < 8; ++oc) pk[oc] = f2bf(fmaxf(acc[oc], 0.f));
    *(u16x8*)(out + ((size_t)m * NPX + px) * 64 + og * 8) = pk;
}

// ================= convMFMA, och-split NT tiles (feature convs) ============
template<int W, int NPX, int NT>
__global__ __launch_bounds__(256) void convmfma_kernel(
    const u16* __restrict__ in, const u16* __restrict__ wbf,
    const float* __restrict__ bias, u16* __restrict__ out)
{
    constexpr int H = 32;
    const int t = threadIdx.x;
    const int base = blockIdx.x * 64;
    const int ochb = blockIdx.y * (NT * 16);
    const int m = blockIdx.z;
    const int w = t >> 6, lane = t & 63, q = lane >> 4, l15 = lane & 15;

    const u16* im = in + (size_t)m * NPX * 64;
    const int pxA = base + w * 16 + l15;
    const int yA = pxA / W, xA = pxA - yA * W;
    const bool pxok = (pxA < NPX);

    f32x4 acc[NT];
#pragma unroll
    for (int nt = 0; nt < NT; ++nt) acc[nt] = f32x4{0.f, 0.f, 0.f, 0.f};

#pragma unroll
    for (int tap = 0; tap < 9; ++tap) {
        const int dy = tap / 3 - 1, dx = tap % 3 - 1;
        const bool valid = pxok && (yA + dy >= 0) && (yA + dy < H)
                                && (xA + dx >= 0) && (xA + dx < W);
        const u16* ap = im + (size_t)(pxA + dy * W + dx) * 64;
        FragU a0, a1;
        if (valid) {
            a0 = *(const FragU*)(ap + q * 8);
            a1 = *(const FragU*)(ap + 32 + q * 8);
        } else {
#pragma unroll
            for (int jj = 0; jj < 8; ++jj) { a0.u[jj] = 0; a1.u[jj] = 0; }
        }
#pragma unroll
        for (int nt = 0; nt < NT; ++nt) {
            const u16* bp = wbf + tap * 4096 + (ochb + nt * 16 + l15) * 64;
            FragU b0 = *(const FragU*)(bp + q * 8);
            FragU b1 = *(const FragU*)(bp + 32 + q * 8);
            acc[nt] = __builtin_amdgcn_mfma_f32_16x16x32_bf16(a0.v, b0.v, acc[nt], 0, 0, 0);
            acc[nt] = __builtin_amdgcn_mfma_f32_16x16x32_bf16(a1.v, b1.v, acc[nt], 0, 0, 0);
        }
    }

#pragma unroll
    for (int nt = 0; nt < NT; ++nt) {
        const float bb = bias[ochb + nt * 16 + l15];
#pragma unroll
        for (int e = 0; e < 4; ++e) {
            int pxs = base + w * 16 + q * 4 + e;
            if (pxs < NPX)
                out[((size_t)m * NPX + pxs) * 64 + ochb + nt * 16 + l15] =
                    f2bf(fmaxf(acc[nt][e] + bb, 0.f));
        }
    }
}

// ================= MLP (r9/r10-verified single kernel) =====================
__global__ __launch_bounds__(256, 2) void mlp_mfma_kernel(
    const float* __restrict__ lf, const float* __restrict__ flow,
    const u16* __restrict__ feat,   // [bs][2016][64] bf16
    const u16* __restrict__ w1t, const u16* __restrict__ w2t,
    const float* __restrict__ w1, const float* __restrict__ b1,
    const float* __restrict__ b2,
    const float* __restrict__ w3, const float* __restrict__ b3g,
    const float* __restrict__ cw, const float* __restrict__ cbg,
    float* __restrict__ nv_out, float* __restrict__ cf_out)
{
    constexpr int SBS = 72;
    __shared__ __align__(16) float s_vec[7 * 64];
    __shared__ __align__(16) float s_flow[256];
    __shared__ __align__(16) float s_epi[256];
    __shared__ __align__(16) u16 s_base[256 * SBS];

    const int t = threadIdx.x;
    const int blk = blockIdx.x;
    const int bs = blk >> 7;
    const int n0 = (blk & 127) * 8;
    const int b = bs >> 1, s = bs & 1;
    const int w = t >> 6, lane = t & 63, q = lane >> 4, l15 = lane & 15;

    if (t < 64) {
        s_vec[t]       = b1[t];
        s_vec[64 + t]  = b2[t];
        s_vec[128 + t] = w3[t];
        s_vec[192 + t] = cw[t];
        s_vec[256 + t] = w1[t];            // row 0: flow weight
        s_vec[320 + t] = w1[65 * 64 + t];  // row 65: spatial
        s_vec[384 + t] = w1[66 * 64 + t];  // row 66: ang
    }
    {
        int nl = t >> 5, k = t & 31;
        int n = n0 + nl;
        int a = (bs * 32 + (n >> 5)) * 63 + (n & 31) + k;
        s_flow[t] = flow[a];
        s_epi[t]  = lf[a];
    }
    __syncthreads();

    const float b3s = b3g[0];
    const float cbs = cbg[0];

    FragU w1b[2][4];
#pragma unroll
    for (int ks = 0; ks < 2; ++ks)
#pragma unroll
        for (int nt = 0; nt < 4; ++nt)
            w1b[ks][nt] = *(const FragU*)(w1t + (nt * 16 + l15) * 64 + ks * 32 + q * 8);

    float w1r0pl[4], w1r65pl[4], b1pl[4];
#pragma unroll
    for (int nt = 0; nt < 4; ++nt) {
        int j1 = nt * 16 + l15;
        w1r0pl[nt]  = s_vec[256 + j1];
        w1r65pl[nt] = s_vec[320 + j1];
        b1pl[nt]    = s_vec[j1];
    }

#pragma unroll
    for (int mt = 0; mt < 4; ++mt) {
        const int rbase = w * 64 + mt * 16;
        FragU af[2];
        {
            int r = rbase + l15;
            int n = n0 + (r >> 5);
            int pos = (n >> 5) * 63 + (n & 31) + (r & 31);
            const u16* fp = feat + ((size_t)bs * 2016 + pos) * 64;
            af[0] = *(const FragU*)(fp + q * 8);
            af[1] = *(const FragU*)(fp + 32 + q * 8);
        }
        f32x4 flow4 = *(const f32x4*)(s_flow + rbase + q * 4);
#pragma unroll
        for (int nt = 0; nt < 4; ++nt) {
            f32x4 d = {0.f, 0.f, 0.f, 0.f};
            d = __builtin_amdgcn_mfma_f32_16x16x32_bf16(af[0].v, w1b[0][nt].v, d, 0, 0, 0);
            d = __builtin_amdgcn_mfma_f32_16x16x32_bf16(af[1].v, w1b[1][nt].v, d, 0, 0, 0);
#pragma unroll
            for (int e = 0; e < 4; ++e) {
                int r = rbase + q * 4 + e;
                int k = r & 31;
                float val = d[e] + flow4[e] * w1r0pl[nt]
                          + (float)(k - 16) * w1r65pl[nt] + b1pl[nt];
                s_base[r * SBS + nt * 16 + l15] = f2bf(val);
            }
        }
    }
    __syncthreads();

    FragU w2a[4][2];
#pragma unroll
    for (int mt = 0; mt < 4; ++mt)
#pragma unroll
        for (int ks = 0; ks < 2; ++ks)
            w2a[mt][ks] = *(const FragU*)(w2t + (mt * 16 + l15) * 64 + ks * 32 + q * 8);

    float w66pl[2][8];
#pragma unroll
    for (int ks = 0; ks < 2; ++ks)
#pragma unroll
        for (int jj = 0; jj < 8; ++jj)
            w66pl[ks][jj] = s_vec[384 + ks * 32 + q * 8 + jj];

    float b2pl[4][4], w3pl[4][4], cwpl[4][4];
#pragma unroll
    for (int mt = 0; mt < 4; ++mt)
#pragma unroll
        for (int e = 0; e < 4; ++e) {
            b2pl[mt][e] = s_vec[64 + mt * 16 + q * 4 + e];
            w3pl[mt][e] = s_vec[128 + mt * 16 + q * 4 + e];
            cwpl[mt][e] = s_vec[192 + mt * 16 + q * 4 + e];
        }
    float epi_pl[4];
#pragma unroll
    for (int nt = 0; nt < 4; ++nt) epi_pl[nt] = s_epi[w * 64 + nt * 16 + l15];

    for (int v = 0; v < 7; ++v) {
        float ang = (s == 0) ? -(float)(v + 1) : (float)(7 - v);
        f32x4 acc[4][4];
#pragma unroll
        for (int nt = 0; nt < 4; ++nt) {
            FragU bfr[2];
#pragma unroll
            for (int ks = 0; ks < 2; ++ks) {
                const u16x8 raw = *(const u16x8*)(s_base + (w * 64 + nt * 16 + l15) * SBS + ks * 32 + q * 8);
#pragma unroll
                for (int jj = 0; jj < 8; ++jj) {
                    float xv = bf2f(raw[jj]);
                    float hv = fmaxf(xv + ang * w66pl[ks][jj], 0.f);
                    bfr[ks].u[jj] = f2bf(hv);
                }
            }
#pragma unroll
            for (int mt = 0; mt < 4; ++mt) {
                f32x4 d = {0.f, 0.f, 0.f, 0.f};
                d = __builtin_amdgcn_mfma_f32_16x16x32_bf16(w2a[mt][0].v, bfr[0].v, d, 0, 0, 0);
                d = __builtin_amdgcn_mfma_f32_16x16x32_bf16(w2a[mt][1].v, bfr[1].v, d, 0, 0, 0);
                acc[mt][nt] = d;
            }
        }
        float wl[4], cfl[4];
#pragma unroll
        for (int nt = 0; nt < 4; ++nt) {
            float wls = 0.f, cfs = 0.f;
#pragma unroll
            for (int mt = 0; mt < 4; ++mt)
#pragma unroll
                for (int e = 0; e < 4; ++e) {
                    float h2 = fmaxf(acc[mt][nt][e] + b2pl[mt][e], 0.f);
                    wls += h2 * w3pl[mt][e];
                    cfs += h2 * cwpl[mt][e];
                }
            wls += __shfl_xor(wls, 16); wls += __shfl_xor(wls, 32);
            cfs += __shfl_xor(cfs, 16); cfs += __shfl_xor(cfs, 32);
            wl[nt]  = wls + b3s;
            cfl[nt] = cfs;
        }
#pragma unroll
        for (int ni = 0; ni < 2; ++ni) {
            float a0 = wl[ni * 2], a1 = wl[ni * 2 + 1];
            float mx = fmaxf(a0, a1);
#pragma unroll
            for (int msk = 1; msk <= 8; msk <<= 1) mx = fmaxf(mx, __shfl_xor(mx, msk));
            float e0 = __expf(a0 - mx), e1 = __expf(a1 - mx);
            float ssum = e0 + e1;
            float nvp = e0 * epi_pl[ni * 2] + e1 * epi_pl[ni * 2 + 1];
            float cfp = cfl[ni * 2] + cfl[ni * 2 + 1];
#pragma unroll
            for (int msk = 1; msk <= 8; msk <<= 1) {
                ssum += __shfl_xor(ssum, msk);
                nvp  += __shfl_xor(nvp, msk);
                cfp  += __shfl_xor(cfp, msk);
            }
            if (lane == 0) {
                int n = n0 + w * 2 + ni;
                size_t idx = ((size_t)(b * 7 + v) * 2 + s) * 1024 + n;
                nv_out[idx] = nvp / ssum;
                cf_out[idx] = cfp * (1.f / 32.f) + cbs;
            }
        }
    }
}

// ================= fused refine: conf-combine + conv1 + conv2 + conv3 ======
// grid (8, 14): 4-row output stripe per block, halo recompute in LDS.
// No cross-block dependency: conv1/conv2 rows are recomputed into LDS with
// full halo, XOR-swizzled (byte ^= (px&7)<<4) for bank-conflict-free MFMA
// A-reads (G4). Arithmetic order replicates the verified split kernels.
__global__ __launch_bounds__(512) void refine_kernel(
    const float* __restrict__ nv, const float* __restrict__ cf,
    const float* __restrict__ pl, const float* __restrict__ pr,
    const float* __restrict__ vrw1, const float* __restrict__ vrb1,
    const u16* __restrict__ wbv, const float* __restrict__ vrb2,
    const float* __restrict__ vrw3, const float* __restrict__ vrb3,
    float* __restrict__ out)
{
    __shared__ __align__(16) float pn_s[10][32];        // pn rows y0-3..y0+6
    __shared__ __align__(16) float sw3[576];            // vrw3 staged
    __shared__ __align__(16) u16 g1_s[8 * 32 * 64];     // conv1 out, rows y0-2..y0+5
    __shared__ __align__(16) u16 g2_s[6 * 32 * 64];     // conv2 out, rows y0-1..y0+4

    const int t = threadIdx.x;
    const int pt = blockIdx.x;          // 0..7  (4-row stripes)
    const int m  = blockIdx.y;          // 0..13
    const int y0 = pt * 4;

    // ---- phase A: conf-softmax combine into pn_s; stage vrw3 --------------
    if (t < 320) {
        int rr = t >> 5, col = t & 31;
        int gy = y0 - 3 + rr;
        float vv = 0.f;
        if (gy >= 0 && gy < 32) {
            int n = gy * 32 + col;
            size_t i0 = ((size_t)m * 2) * 1024 + n;
            size_t i1 = i0 + 1024;
            float c0 = cf[i0], c1 = cf[i1];
            float mx = fmaxf(c0, c1);
            float e0 = __expf(c0 - mx), e1 = __expf(c1 - mx);
            vv = (e0 * nv[i0] + e1 * nv[i1]) / (e0 + e1);
        }
        pn_s[rr][col] = vv;
    }
    for (int i = t; i < 576; i += 512) sw3[i] = vrw3[i];
    __syncthreads();

    // ---- phase B: conv1 (3->64), scalar f32 (numerics-identical) ----------
    {
        const int px_i = t >> 1;              // 0..255 over 8 g1 rows
        const int oh   = t & 1;               // och half
        const int lr0  = px_i >> 5;           // g1 local row
        const int x    = px_i & 31;
        const int gy   = y0 - 2 + lr0;
        const bool inimg = (gy >= 0) && (gy < 32);

        float tap0[9], tap1[9], tap2[9];
        if (inimg) {
            const float* plm = pl + (size_t)m * 1024;
            const float* prm = pr + (size_t)m * 1024;
#pragma unroll
            for (int dy = 0; dy < 3; ++dy) {
                int prow = lr0 + dy;          // pn_s local row
                int yy = gy + dy - 1;
                bool ry = (yy >= 0) && (yy < 32);
#pragma unroll
                for (int dx = 0; dx < 3; ++dx) {
                    int xx = x + dx - 1;
                    bool rx = (xx >= 0) && (xx < 32);
                    tap0[dy * 3 + dx] = rx ? pn_s[prow][xx] : 0.f;
                    tap1[dy * 3 + dx] = (ry && rx) ? plm[yy * 32 + xx] : 0.f;
                    tap2[dy * 3 + dx] = (ry && rx) ? prm[yy * 32 + xx] : 0.f;
                }
            }
        }
#pragma unroll
        for (int jg = 0; jg < 4; ++jg) {
            u16x8 pk;
#pragma unroll
            for (int e = 0; e < 8; ++e) {
                float acc = 0.f;
                if (inimg) {
                    int o = oh * 32 + jg * 8 + e;
                    const float* wr = vrw1 + (size_t)o * 27;
                    acc = vrb1[o];
#pragma unroll
                    for (int j = 0; j < 9; ++j) acc = fmaf(tap0[j], wr[j], acc);
#pragma unroll
                    for (int j = 0; j < 9; ++j) acc = fmaf(tap1[j], wr[9 + j], acc);
#pragma unroll
                    for (int j = 0; j < 9; ++j) acc = fmaf(tap2[j], wr[18 + j], acc);
                    acc = fmaxf(acc, 0.f);
                }
                pk[e] = f2bf(acc);
            }
            int byte = (px_i * 128 + oh * 64 + jg * 16) ^ ((px_i & 7) << 4);
            *(u16x8*)((char*)g1_s + byte) = pk;
        }
    }
    __syncthreads();

    // ---- phase C: conv2 (64->64) via MFMA from LDS ------------------------
    {
        const int w = t >> 6, lane = t & 63, q = lane >> 4, l15 = lane & 15;
        const int ocht = w & 3, base = ocht * 16;
        const int wg = w >> 2;                // 0..1

        f32x4 acc[6];
#pragma unroll
        for (int i = 0; i < 6; ++i) acc[i] = f32x4{0.f, 0.f, 0.f, 0.f};

#pragma unroll
        for (int tap = 0; tap < 9; ++tap) {
            const int dy = tap / 3 - 1, dx = tap % 3 - 1;
            const u16* bp = wbv + tap * 4096 + (base + l15) * 64;
            FragU b0 = *(const FragU*)(bp + q * 8);
            FragU b1 = *(const FragU*)(bp + 32 + q * 8);
#pragma unroll
            for (int i = 0; i < 6; ++i) {
                const int p = (wg + 2 * i) * 16 + l15;     // g2 local px 0..191
                const int xx = (p & 31) + dx;
                const int p1 = p + (dy + 1) * 32 + dx;     // g1 local px
                FragU a0, a1;
                if (xx >= 0 && xx < 32) {
                    int byte = (p1 * 128 + q * 16) ^ ((p1 & 7) << 4);
                    a0 = *(const FragU*)((const char*)g1_s + byte);
                    byte = (p1 * 128 + 64 + q * 16) ^ ((p1 & 7) << 4);
                    a1 = *(const FragU*)((const char*)g1_s + byte);
                } else {
#pragma unroll
                    for (int jj = 0; jj < 8; ++jj) { a0.u[jj] = 0; a1.u[jj] = 0; }
                }
                acc[i] = __builtin_amdgcn_mfma_f32_16x16x32_bf16(a0.v, b0.v, acc[i], 0, 0, 0);
                acc[i] = __builtin_amdgcn_mfma_f32_16x16x32_bf16(a1.v, b1.v, acc[i], 0, 0, 0);
            }
        }

        const float bb = vrb2[base + l15];
#pragma unroll
        for (int i = 0; i < 6; ++i) {
#pragma unroll
            for (int e = 0; e < 4; ++e) {
                int p = (wg + 2 * i) * 16 + q * 4 + e;
                int gy2 = y0 - 1 + (p >> 5);
                float vv = (gy2 >= 0 && gy2 < 32) ? fmaxf(acc[i][e] + bb, 0.f) : 0.f;
                int byte = (p * 128 + (base + l15) * 2) ^ ((p & 7) << 4);
                *(u16*)((char*)g2_s + byte) = f2bf(vv);
            }
        }
    }
    __syncthreads();

    // ---- phase D: conv3 (64->1) + residual --------------------------------
    {
        const int px_i = t >> 2;              // 0..127 over 4 out rows
        const int part = t & 3;               // 16-och slice
        const int ly = px_i >> 5;
        const int x  = px_i & 31;

        float a = 0.f;
#pragma unroll
        for (int dy = 0; dy < 3; ++dy) {
#pragma unroll
            for (int dx = 0; dx < 3; ++dx) {
                int xx = x + dx - 1;
                if (xx < 0 || xx >= 32) continue;
                int p2 = px_i + dy * 32 + dx - 1;     // g2 local px
                const int tap = dy * 3 + dx;
                int byte0 = (p2 * 128 + part * 32) ^ ((p2 & 7) << 4);
                int byte1 = (p2 * 128 + part * 32 + 16) ^ ((p2 & 7) << 4);
                u16x8 r0 = *(const u16x8*)((const char*)g2_s + byte0);
                u16x8 r1 = *(const u16x8*)((const char*)g2_s + byte1);
#pragma unroll
                for (int e = 0; e < 8; ++e) {
                    a = fmaf(bf2f(r0[e]), sw3[(part * 16 + e) * 9 + tap], a);
                    a = fmaf(bf2f(r1[e]), sw3[(part * 16 + 8 + e) * 9 + tap], a);
                }
            }
        }
        a += __shfl_xor(a, 1);
        a += __shfl_xor(a, 2);
        if (part == 0) {
            int gy = y0 + ly;
            out[(size_t)m * 1024 + gy * 32 + x] = pn_s[ly + 3][x] + a + vrb3[0];
        }
    }
}

// ---------------- launch ----------------
extern "C" void kernel_launch(void* const* d_in, const int* in_sizes, int n_in,
                              void* d_out, int out_size, void* d_ws, size_t ws_size,
                              hipStream_t stream) {
    const float* lf   = (const float*)d_in[0];
    const float* flow = (const float*)d_in[1];
    const float* wp   = (const float*)d_in[2];
    const float* pl   = (const float*)d_in[3];
    const float* pr   = (const float*)d_in[4];
    float* ws = (float*)d_ws;

    conv1feat_kernel<<<dim3(8, 8, 5), 256, 0, stream>>>(
        flow, lf, wp, (const float*)d_in[5], (const float*)d_in[6],
        (u16*)(ws + X1),
        (const float*)d_in[7], (const float*)d_in[9], (const float*)d_in[21],
        (const float*)d_in[11], (const float*)d_in[13],
        (u16*)(ws + WB2F), (u16*)(ws + WB3F), (u16*)(ws + WBV2),
        (u16*)(ws + W1T), (u16*)(ws + W2T));

    convmfma_kernel<63, 2016, 1><<<dim3(32, 4, 4), 256, 0, stream>>>(
        (const u16*)(ws + X1), (const u16*)(ws + WB2F), (const float*)d_in[8],
        (u16*)(ws + X2));
    convmfma_kernel<63, 2016, 1><<<dim3(32, 4, 4), 256, 0, stream>>>(
        (const u16*)(ws + X2), (const u16*)(ws + WB3F), (const float*)d_in[10],
        (u16*)(ws + FEATBF));

    mlp_mfma_kernel<<<512, 256, 0, stream>>>(
        lf, flow, (const u16*)(ws + FEATBF),
        (const u16*)(ws + W1T), (const u16*)(ws + W2T),
        (const float*)d_in[11], (const float*)d_in[12],
        (const float*)d_in[14],
        (const float*)d_in[15], (const float*)d_in[16],
        (const float*)d_in[17], (const float*)d_in[18],
        ws + NVOFF, ws + CFOFF);

    refine_kernel<<<dim3(8, 14), 512, 0, stream>>>(
        ws + NVOFF, ws + CFOFF, pl, pr,
        (const float*)d_in[19], (const float*)d_in[20],
        (const u16*)(ws + WBV2), (const float*)d_in[22],
        (const float*)d_in[23], (const float*)d_in[24],
        (float*)d_out);
}

// Round 3
// 179.489 us; speedup vs baseline: 3.0297x; 1.0546x over previous
//
#include <hip/hip_runtime.h>

typedef unsigned short u16;
typedef unsigned int u32;
typedef __bf16 bf16x8 __attribute__((ext_vector_type(8)));
typedef float f32x4 __attribute__((ext_vector_type(4)));
typedef u16 u16x8 __attribute__((ext_vector_type(8)));

__device__ __forceinline__ u16 f2bf(float f) {
    __bf16 h = (__bf16)f;
    return __builtin_bit_cast(u16, h);
}
__device__ __forceinline__ float bf2f(u16 u) {
    unsigned int x = ((unsigned int)u) << 16;
    return __builtin_bit_cast(float, x);
}

union FragU { u16x8 u; bf16x8 v; };

// ---------------- workspace layout (float offsets) ----------------
constexpr size_t WB2F  = 0;        // frw2 bf16 [tap][och][cin]
constexpr size_t WB3F  = 18432;    // frw3
constexpr size_t WBV2  = 36864;    // vrw2
constexpr size_t W1T   = 55296;    // mw1 rows 1..64, [col][row-1]
constexpr size_t W2T   = 57344;    // mw2 transposed [j2][j1]
constexpr size_t X1    = 59392;    // 4*2016*64 u16 (ch-last bf16)
constexpr size_t X2    = 317440;
constexpr size_t FEATBF= 575488;
constexpr size_t NVOFF = 833536;   // [(b*7+v)*2+s][1024]
constexpr size_t CFOFF = 862208;

// ================= D1: feature conv1 (3->64) + weight prep ================
__global__ __launch_bounds__(256) void conv1feat_kernel(
    const float* __restrict__ in0, const float* __restrict__ in1,
    const float* __restrict__ in2,
    const float* __restrict__ wts, const float* __restrict__ bias,
    u16* __restrict__ out,
    const float* __restrict__ frw2, const float* __restrict__ frw3,
    const float* __restrict__ vrw2,
    const float* __restrict__ mw1, const float* __restrict__ mw2,
    u16* __restrict__ wb2, u16* __restrict__ wb3, u16* __restrict__ wbv,
    u16* __restrict__ w1t, u16* __restrict__ w2t)
{
    constexpr int W = 63, NPX = 2016, H = 32;
    const int t = threadIdx.x;
    if (blockIdx.z == 4) {
        const int tid = (blockIdx.y * 8 + blockIdx.x) * 256 + t;
        for (int i = tid; i < 36864; i += 16384) {
            int tap = i >> 12, och = (i >> 6) & 63, cin = i & 63;
            size_t s = (size_t)och * 576 + cin * 9 + tap;
            wb2[i] = f2bf(frw2[s]);
            wb3[i] = f2bf(frw3[s]);
            wbv[i] = f2bf(vrw2[s]);
        }
        for (int i = tid; i < 4096; i += 16384) {
            int col = i >> 6, r = i & 63;
            w1t[i] = f2bf(mw1[(1 + r) * 64 + col]);
            w2t[i] = f2bf(mw2[r * 64 + col]);
        }
        return;
    }
    const int px = blockIdx.y * 256 + t;
    const int m = blockIdx.z;
    const int og = blockIdx.x;
    if (px >= NPX) return;
    const int y = px / W, x = px - y * W;

    float acc[8];
#pragma unroll
    for (int oc = 0; oc < 8; ++oc) acc[oc] = bias[og * 8 + oc];

#pragma unroll
    for (int cin = 0; cin < 3; ++cin) {
        const float* ip = (cin == 0 ? in0 : (cin == 1 ? in1 : in2)) + (size_t)m * NPX;
        float tap[9];
#pragma unroll
        for (int dy = 0; dy < 3; ++dy) {
            int yy = y + dy - 1;
            bool ry = (yy >= 0) && (yy < H);
#pragma unroll
            for (int dx = 0; dx < 3; ++dx) {
                int xx = x + dx - 1;
                tap[dy * 3 + dx] = (ry && xx >= 0 && xx < W) ? ip[yy * W + xx] : 0.f;
            }
        }
#pragma unroll
        for (int oc = 0; oc < 8; ++oc) {
            const float* wr = wts + (size_t)(og * 8 + oc) * 27 + cin * 9;
#pragma unroll
            for (int j = 0; j < 9; ++j) acc[oc] = fmaf(tap[j], wr[j], acc[oc]);
        }
    }
    u16x8 pk;
#pragma unroll
    for (int oc = 0; oc < 8; ++oc) pk[oc] = f2bf(fmaxf(acc[oc], 0.f));
    *(u16x8*)(out + ((size_t)m * NPX + px) * 64 + og * 8) = pk;
}

// ================= convMFMA, och-split NT tiles (feature convs) ============
template<int W, int NPX, int NT>
__global__ __launch_bounds__(256) void convmfma_kernel(
    const u16* __restrict__ in, const u16* __restrict__ wbf,
    const float* __restrict__ bias, u16* __restrict__ out)
{
    constexpr int H = 32;
    const int t = threadIdx.x;
    const int base = blockIdx.x * 64;
    const int ochb = blockIdx.y * (NT * 16);
    const int m = blockIdx.z;
    const int w = t >> 6, lane = t & 63, q = lane >> 4, l15 = lane & 15;

    const u16* im = in + (size_t)m * NPX * 64;
    const int pxA = base + w * 16 + l15;
    const int yA = pxA / W, xA = pxA - yA * W;
    const bool pxok = (pxA < NPX);

    f32x4 acc[NT];
#pragma unroll
    for (int nt = 0; nt < NT; ++nt) acc[nt] = f32x4{0.f, 0.f, 0.f, 0.f};

#pragma unroll
    for (int tap = 0; tap < 9; ++tap) {
        const int dy = tap / 3 - 1, dx = tap % 3 - 1;
        const bool valid = pxok && (yA + dy >= 0) && (yA + dy < H)
                                && (xA + dx >= 0) && (xA + dx < W);
        const u16* ap = im + (size_t)(pxA + dy * W + dx) * 64;
        FragU a0, a1;
        if (valid) {
            a0 = *(const FragU*)(ap + q * 8);
            a1 = *(const FragU*)(ap + 32 + q * 8);
        } else {
#pragma unroll
            for (int jj = 0; jj < 8; ++jj) { a0.u[jj] = 0; a1.u[jj] = 0; }
        }
#pragma unroll
        for (int nt = 0; nt < NT; ++nt) {
            const u16* bp = wbf + tap * 4096 + (ochb + nt * 16 + l15) * 64;
            FragU b0 = *(const FragU*)(bp + q * 8);
            FragU b1 = *(const FragU*)(bp + 32 + q * 8);
            acc[nt] = __builtin_amdgcn_mfma_f32_16x16x32_bf16(a0.v, b0.v, acc[nt], 0, 0, 0);
            acc[nt] = __builtin_amdgcn_mfma_f32_16x16x32_bf16(a1.v, b1.v, acc[nt], 0, 0, 0);
        }
    }

#pragma unroll
    for (int nt = 0; nt < NT; ++nt) {
        const float bb = bias[ochb + nt * 16 + l15];
#pragma unroll
        for (int e = 0; e < 4; ++e) {
            int pxs = base + w * 16 + q * 4 + e;
            if (pxs < NPX)
                out[((size_t)m * NPX + pxs) * 64 + ochb + nt * 16 + l15] =
                    f2bf(fmaxf(acc[nt][e] + bb, 0.f));
        }
    }
}

// ================= MLP (r9/r10-verified single kernel) =====================
__global__ __launch_bounds__(256, 2) void mlp_mfma_kernel(
    const float* __restrict__ lf, const float* __restrict__ flow,
    const u16* __restrict__ feat,   // [bs][2016][64] bf16
    const u16* __restrict__ w1t, const u16* __restrict__ w2t,
    const float* __restrict__ w1, const float* __restrict__ b1,
    const float* __restrict__ b2,
    const float* __restrict__ w3, const float* __restrict__ b3g,
    const float* __restrict__ cw, const float* __restrict__ cbg,
    float* __restrict__ nv_out, float* __restrict__ cf_out)
{
    constexpr int SBS = 72;
    __shared__ __align__(16) float s_vec[7 * 64];
    __shared__ __align__(16) float s_flow[256];
    __shared__ __align__(16) float s_epi[256];
    __shared__ __align__(16) u16 s_base[256 * SBS];

    const int t = threadIdx.x;
    const int blk = blockIdx.x;
    const int bs = blk >> 7;
    const int n0 = (blk & 127) * 8;
    const int b = bs >> 1, s = bs & 1;
    const int w = t >> 6, lane = t & 63, q = lane >> 4, l15 = lane & 15;

    if (t < 64) {
        s_vec[t]       = b1[t];
        s_vec[64 + t]  = b2[t];
        s_vec[128 + t] = w3[t];
        s_vec[192 + t] = cw[t];
        s_vec[256 + t] = w1[t];            // row 0: flow weight
        s_vec[320 + t] = w1[65 * 64 + t];  // row 65: spatial
        s_vec[384 + t] = w1[66 * 64 + t];  // row 66: ang
    }
    {
        int nl = t >> 5, k = t & 31;
        int n = n0 + nl;
        int a = (bs * 32 + (n >> 5)) * 63 + (n & 31) + k;
        s_flow[t] = flow[a];
        s_epi[t]  = lf[a];
    }
    __syncthreads();

    const float b3s = b3g[0];
    const float cbs = cbg[0];

    FragU w1b[2][4];
#pragma unroll
    for (int ks = 0; ks < 2; ++ks)
#pragma unroll
        for (int nt = 0; nt < 4; ++nt)
            w1b[ks][nt] = *(const FragU*)(w1t + (nt * 16 + l15) * 64 + ks * 32 + q * 8);

    float w1r0pl[4], w1r65pl[4], b1pl[4];
#pragma unroll
    for (int nt = 0; nt < 4; ++nt) {
        int j1 = nt * 16 + l15;
        w1r0pl[nt]  = s_vec[256 + j1];
        w1r65pl[nt] = s_vec[320 + j1];
        b1pl[nt]    = s_vec[j1];
    }

#pragma unroll
    for (int mt = 0; mt < 4; ++mt) {
        const int rbase = w * 64 + mt * 16;
        FragU af[2];
        {
            int r = rbase + l15;
            int n = n0 + (r >> 5);
            int pos = (n >> 5) * 63 + (n & 31) + (r & 31);
            const u16* fp = feat + ((size_t)bs * 2016 + pos) * 64;
            af[0] = *(const FragU*)(fp + q * 8);
            af[1] = *(const FragU*)(fp + 32 + q * 8);
        }
        f32x4 flow4 = *(const f32x4*)(s_flow + rbase + q * 4);
#pragma unroll
        for (int nt = 0; nt < 4; ++nt) {
            f32x4 d = {0.f, 0.f, 0.f, 0.f};
            d = __builtin_amdgcn_mfma_f32_16x16x32_bf16(af[0].v, w1b[0][nt].v, d, 0, 0, 0);
            d = __builtin_amdgcn_mfma_f32_16x16x32_bf16(af[1].v, w1b[1][nt].v, d, 0, 0, 0);
#pragma unroll
            for (int e = 0; e < 4; ++e) {
                int r = rbase + q * 4 + e;
                int k = r & 31;
                float val = d[e] + flow4[e] * w1r0pl[nt]
                          + (float)(k - 16) * w1r65pl[nt] + b1pl[nt];
                s_base[r * SBS + nt * 16 + l15] = f2bf(val);
            }
        }
    }
    __syncthreads();

    FragU w2a[4][2];
#pragma unroll
    for (int mt = 0; mt < 4; ++mt)
#pragma unroll
        for (int ks = 0; ks < 2; ++ks)
            w2a[mt][ks] = *(const FragU*)(w2t + (mt * 16 + l15) * 64 + ks * 32 + q * 8);

    float w66pl[2][8];
#pragma unroll
    for (int ks = 0; ks < 2; ++ks)
#pragma unroll
        for (int jj = 0; jj < 8; ++jj)
            w66pl[ks][jj] = s_vec[384 + ks * 32 + q * 8 + jj];

    float b2pl[4][4], w3pl[4][4], cwpl[4][4];
#pragma unroll
    for (int mt = 0; mt < 4; ++mt)
#pragma unroll
        for (int e = 0; e < 4; ++e) {
            b2pl[mt][e] = s_vec[64 + mt * 16 + q * 4 + e];
            w3pl[mt][e] = s_vec[128 + mt * 16 + q * 4 + e];
            cwpl[mt][e] = s_vec[192 + mt * 16 + q * 4 + e];
        }
    float epi_pl[4];
#pragma unroll
    for (int nt = 0; nt < 4; ++nt) epi_pl[nt] = s_epi[w * 64 + nt * 16 + l15];

    for (int v = 0; v < 7; ++v) {
        float ang = (s == 0) ? -(float)(v + 1) : (float)(7 - v);
        f32x4 acc[4][4];
#pragma unroll
        for (int nt = 0; nt < 4; ++nt) {
            FragU bfr[2];
#pragma unroll
            for (int ks = 0; ks < 2; ++ks) {
                const u16x8 raw = *(const u16x8*)(s_base + (w * 64 + nt * 16 + l15) * SBS + ks * 32 + q * 8);
#pragma unroll
                for (int jj = 0; jj < 8; ++jj) {
                    float xv = bf2f(raw[jj]);
                    float hv = fmaxf(xv + ang * w66pl[ks][jj], 0.f);
                    bfr[ks].u[jj] = f2bf(hv);
                }
            }
#pragma unroll
            for (int mt = 0; mt < 4; ++mt) {
                f32x4 d = {0.f, 0.f, 0.f, 0.f};
                d = __builtin_amdgcn_mfma_f32_16x16x32_bf16(w2a[mt][0].v, bfr[0].v, d, 0, 0, 0);
                d = __builtin_amdgcn_mfma_f32_16x16x32_bf16(w2a[mt][1].v, bfr[1].v, d, 0, 0, 0);
                acc[mt][nt] = d;
            }
        }
        float wl[4], cfl[4];
#pragma unroll
        for (int nt = 0; nt < 4; ++nt) {
            float wls = 0.f, cfs = 0.f;
#pragma unroll
            for (int mt = 0; mt < 4; ++mt)
#pragma unroll
                for (int e = 0; e < 4; ++e) {
                    float h2 = fmaxf(acc[mt][nt][e] + b2pl[mt][e], 0.f);
                    wls += h2 * w3pl[mt][e];
                    cfs += h2 * cwpl[mt][e];
                }
            wls += __shfl_xor(wls, 16); wls += __shfl_xor(wls, 32);
            cfs += __shfl_xor(cfs, 16); cfs += __shfl_xor(cfs, 32);
            wl[nt]  = wls + b3s;
            cfl[nt] = cfs;
        }
#pragma unroll
        for (int ni = 0; ni < 2; ++ni) {
            float a0 = wl[ni * 2], a1 = wl[ni * 2 + 1];
            float mx = fmaxf(a0, a1);
#pragma unroll
            for (int msk = 1; msk <= 8; msk <<= 1) mx = fmaxf(mx, __shfl_xor(mx, msk));
            float e0 = __expf(a0 - mx), e1 = __expf(a1 - mx);
            float ssum = e0 + e1;
            float nvp = e0 * epi_pl[ni * 2] + e1 * epi_pl[ni * 2 + 1];
            float cfp = cfl[ni * 2] + cfl[ni * 2 + 1];
#pragma unroll
            for (int msk = 1; msk <= 8; msk <<= 1) {
                ssum += __shfl_xor(ssum, msk);
                nvp  += __shfl_xor(nvp, msk);
                cfp  += __shfl_xor(cfp, msk);
            }
            if (lane == 0) {
                int n = n0 + w * 2 + ni;
                size_t idx = ((size_t)(b * 7 + v) * 2 + s) * 1024 + n;
                nv_out[idx] = nvp / ssum;
                cf_out[idx] = cfp * (1.f / 32.f) + cbs;
            }
        }
    }
}

// ================= fused refine: conf-combine + conv1 + conv2 + conv3 ======
// grid (8, 14): 4-row output stripe per block, halo recompute in LDS.
// r3: phase-B weights via wave-uniform (SGPR) addressing; pl/pr staged in
// LDS; __launch_bounds__(512,4) so the allocator can pipeline loads
// (r2's VGPR=52 build was global-latency serialized: 40 us, VALUBusy 7%).
__global__ __launch_bounds__(512, 4) void refine_kernel(
    const float* __restrict__ nv, const float* __restrict__ cf,
    const float* __restrict__ pl, const float* __restrict__ pr,
    const float* __restrict__ vrw1, const float* __restrict__ vrb1,
    const u16* __restrict__ wbv, const float* __restrict__ vrb2,
    const float* __restrict__ vrw3, const float* __restrict__ vrb3,
    float* __restrict__ out)
{
    __shared__ __align__(16) float pn_s[10][32];        // pn rows y0-3..y0+6
    __shared__ __align__(16) float pls[10][32];         // patch_left rows (0 off-image)
    __shared__ __align__(16) float prs[10][32];         // patch_right rows
    __shared__ __align__(16) float sw3[576];            // vrw3 staged
    __shared__ __align__(16) u16 g1_s[8 * 32 * 64];     // conv1 out, rows y0-2..y0+5
    __shared__ __align__(16) u16 g2_s[6 * 32 * 64];     // conv2 out, rows y0-1..y0+4

    const int t = threadIdx.x;
    const int pt = blockIdx.x;          // 0..7  (4-row stripes)
    const int m  = blockIdx.y;          // 0..13
    const int y0 = pt * 4;

    // ---- phase A: conf-softmax combine into pn_s; stage pl/pr + vrw3 ------
    if (t < 320) {
        int rr = t >> 5, col = t & 31;
        int gy = y0 - 3 + rr;
        float vv = 0.f, vl = 0.f, vr = 0.f;
        if (gy >= 0 && gy < 32) {
            int n = gy * 32 + col;
            size_t i0 = ((size_t)m * 2) * 1024 + n;
            size_t i1 = i0 + 1024;
            float c0 = cf[i0], c1 = cf[i1];
            float mx = fmaxf(c0, c1);
            float e0 = __expf(c0 - mx), e1 = __expf(c1 - mx);
            vv = (e0 * nv[i0] + e1 * nv[i1]) / (e0 + e1);
            vl = pl[(size_t)m * 1024 + n];
            vr = pr[(size_t)m * 1024 + n];
        }
        pn_s[rr][col] = vv;
        pls[rr][col] = vl;
        prs[rr][col] = vr;
    }
    for (int i = t; i < 576; i += 512) sw3[i] = vrw3[i];
    __syncthreads();

    // ---- phase B: conv1 (3->64), wave-uniform weights (SGPR) --------------
    {
        const int wv = __builtin_amdgcn_readfirstlane(t >> 6);  // 0..7, uniform
        const int lane = t & 63;
        const int oh = wv & 1;                 // och half (uniform per wave)
        const int px_i = (wv >> 1) * 64 + lane;   // 0..255 over 8 g1 rows
        const int lr0 = px_i >> 5;             // g1 local row
        const int x = px_i & 31;
        const int gy = y0 - 2 + lr0;
        const bool inimg = (gy >= 0) && (gy < 32);

        float tap0[9], tap1[9], tap2[9];
#pragma unroll
        for (int dy = 0; dy < 3; ++dy) {
            const int prow = lr0 + dy;         // LDS row for yy = gy+dy-1
#pragma unroll
            for (int dx = 0; dx < 3; ++dx) {
                int xx = x + dx - 1;
                bool rx = (xx >= 0) && (xx < 32);
                tap0[dy * 3 + dx] = rx ? pn_s[prow][xx] : 0.f;
                tap1[dy * 3 + dx] = rx ? pls[prow][xx] : 0.f;
                tap2[dy * 3 + dx] = rx ? prs[prow][xx] : 0.f;
            }
        }
#pragma unroll
        for (int jg = 0; jg < 4; ++jg) {
            u16x8 pk;
#pragma unroll
            for (int e = 0; e < 8; ++e) {
                const int o = oh * 32 + jg * 8 + e;   // uniform per wave
                const float* wr = vrw1 + (size_t)o * 27;
                float acc = vrb1[o];
#pragma unroll
                for (int j = 0; j < 9; ++j) acc = fmaf(tap0[j], wr[j], acc);
#pragma unroll
                for (int j = 0; j < 9; ++j) acc = fmaf(tap1[j], wr[9 + j], acc);
#pragma unroll
                for (int j = 0; j < 9; ++j) acc = fmaf(tap2[j], wr[18 + j], acc);
                pk[e] = f2bf(inimg ? fmaxf(acc, 0.f) : 0.f);
            }
            int byte = (px_i * 128 + oh * 64 + jg * 16) ^ ((px_i & 7) << 4);
            *(u16x8*)((char*)g1_s + byte) = pk;
        }
    }
    __syncthreads();

    // ---- phase C: conv2 (64->64) via MFMA from LDS ------------------------
    {
        const int w = t >> 6, lane = t & 63, q = lane >> 4, l15 = lane & 15;
        const int ocht = w & 3, base = ocht * 16;
        const int wg = w >> 2;                // 0..1

        f32x4 acc[6];
#pragma unroll
        for (int i = 0; i < 6; ++i) acc[i] = f32x4{0.f, 0.f, 0.f, 0.f};

#pragma unroll
        for (int tap = 0; tap < 9; ++tap) {
            const int dy = tap / 3 - 1, dx = tap % 3 - 1;
            const u16* bp = wbv + tap * 4096 + (base + l15) * 64;
            FragU b0 = *(const FragU*)(bp + q * 8);
            FragU b1 = *(const FragU*)(bp + 32 + q * 8);
#pragma unroll
            for (int i = 0; i < 6; ++i) {
                const int p = (wg + 2 * i) * 16 + l15;     // g2 local px 0..191
                const int xx = (p & 31) + dx;
                const int p1 = p + (dy + 1) * 32 + dx;     // g1 local px
                FragU a0, a1;
                if (xx >= 0 && xx < 32) {
                    int byte = (p1 * 128 + q * 16) ^ ((p1 & 7) << 4);
                    a0 = *(const FragU*)((const char*)g1_s + byte);
                    byte = (p1 * 128 + 64 + q * 16) ^ ((p1 & 7) << 4);
                    a1 = *(const FragU*)((const char*)g1_s + byte);
                } else {
#pragma unroll
                    for (int jj = 0; jj < 8; ++jj) { a0.u[jj] = 0; a1.u[jj] = 0; }
                }
                acc[i] = __builtin_amdgcn_mfma_f32_16x16x32_bf16(a0.v, b0.v, acc[i], 0, 0, 0);
                acc[i] = __builtin_amdgcn_mfma_f32_16x16x32_bf16(a1.v, b1.v, acc[i], 0, 0, 0);
            }
        }

        const float bb = vrb2[base + l15];
#pragma unroll
        for (int i = 0; i < 6; ++i) {
#pragma unroll
            for (int e = 0; e < 4; ++e) {
                int p = (wg + 2 * i) * 16 + q * 4 + e;
                int gy2 = y0 - 1 + (p >> 5);
                float vv = (gy2 >= 0 && gy2 < 32) ? fmaxf(acc[i][e] + bb, 0.f) : 0.f;
                int byte = (p * 128 + (base + l15) * 2) ^ ((p & 7) << 4);
                *(u16*)((char*)g2_s + byte) = f2bf(vv);
            }
        }
    }
    __syncthreads();

    // ---- phase D: conv3 (64->1) + residual --------------------------------
    {
        const int px_i = t >> 2;              // 0..127 over 4 out rows
        const int part = t & 3;               // 16-och slice
        const int ly = px_i >> 5;
        const int x  = px_i & 31;

        float a = 0.f;
#pragma unroll
        for (int dy = 0; dy < 3; ++dy) {
#pragma unroll
            for (int dx = 0; dx < 3; ++dx) {
                int xx = x + dx - 1;
                if (xx < 0 || xx >= 32) continue;
                int p2 = px_i + dy * 32 + dx - 1;     // g2 local px
                const int tap = dy * 3 + dx;
                int byte0 = (p2 * 128 + part * 32) ^ ((p2 & 7) << 4);
                int byte1 = (p2 * 128 + part * 32 + 16) ^ ((p2 & 7) << 4);
                u16x8 r0 = *(const u16x8*)((const char*)g2_s + byte0);
                u16x8 r1 = *(const u16x8*)((const char*)g2_s + byte1);
#pragma unroll
                for (int e = 0; e < 8; ++e) {
                    a = fmaf(bf2f(r0[e]), sw3[(part * 16 + e) * 9 + tap], a);
                    a = fmaf(bf2f(r1[e]), sw3[(part * 16 + 8 + e) * 9 + tap], a);
                }
            }
        }
        a += __shfl_xor(a, 1);
        a += __shfl_xor(a, 2);
        if (part == 0) {
            int gy = y0 + ly;
            out[(size_t)m * 1024 + gy * 32 + x] = pn_s[ly + 3][x] + a + vrb3[0];
        }
    }
}

// ---------------- launch ----------------
extern "C" void kernel_launch(void* const* d_in, const int* in_sizes, int n_in,
                              void* d_out, int out_size, void* d_ws, size_t ws_size,
                              hipStream_t stream) {
    const float* lf   = (const float*)d_in[0];
    const float* flow = (const float*)d_in[1];
    const float* wp   = (const float*)d_in[2];
    const float* pl   = (const float*)d_in[3];
    const float* pr   = (const float*)d_in[4];
    float* ws = (float*)d_ws;

    conv1feat_kernel<<<dim3(8, 8, 5), 256, 0, stream>>>(
        flow, lf, wp, (const float*)d_in[5], (const float*)d_in[6],
        (u16*)(ws + X1),
        (const float*)d_in[7], (const float*)d_in[9], (const float*)d_in[21],
        (const float*)d_in[11], (const float*)d_in[13],
        (u16*)(ws + WB2F), (u16*)(ws + WB3F), (u16*)(ws + WBV2),
        (u16*)(ws + W1T), (u16*)(ws + W2T));

    convmfma_kernel<63, 2016, 1><<<dim3(32, 4, 4), 256, 0, stream>>>(
        (const u16*)(ws + X1), (const u16*)(ws + WB2F), (const float*)d_in[8],
        (u16*)(ws + X2));
    convmfma_kernel<63, 2016, 1><<<dim3(32, 4, 4), 256, 0, stream>>>(
        (const u16*)(ws + X2), (const u16*)(ws + WB3F), (const float*)d_in[10],
        (u16*)(ws + FEATBF));

    mlp_mfma_kernel<<<512, 256, 0, stream>>>(
        lf, flow, (const u16*)(ws + FEATBF),
        (const u16*)(ws + W1T), (const u16*)(ws + W2T),
        (const float*)d_in[11], (const float*)d_in[12],
        (const float*)d_in[14],
        (const float*)d_in[15], (const float*)d_in[16],
        (const float*)d_in[17], (const float*)d_in[18],
        ws + NVOFF, ws + CFOFF);

    refine_kernel<<<dim3(8, 14), 512, 0, stream>>>(
        ws + NVOFF, ws + CFOFF, pl, pr,
        (const float*)d_in[19], (const float*)d_in[20],
        (const u16*)(ws + WBV2), (const float*)d_in[22],
        (const float*)d_in[23], (const float*)d_in[24],
        (float*)d_out);
}